// Round 1
// baseline (607.939 us; speedup 1.0000x reference)
//
#include <hip/hip_runtime.h>
#include <hip/hip_bf16.h>
#include <stdint.h>

// Problem constants (B,L,D,H,UNITS = 64,1024,1024,1024,1024)
#define B_ 64
#define L_ 1024
#define D_ 1024
#define U_ 1024
#define M_ (B_ * L_)  // 65536 rows of the big GEMM

typedef __attribute__((ext_vector_type(8))) __bf16 bf16x8;
typedef __attribute__((ext_vector_type(4))) float f32x4;

// fp32 -> bf16 with round-to-nearest-even
__device__ __forceinline__ unsigned short f2bf(float f) {
  unsigned u = __float_as_uint(f);
  unsigned r = (u + 0x7fffu + ((u >> 16) & 1u)) >> 16;
  return (unsigned short)r;
}

__device__ __forceinline__ float bf2f(unsigned short h) {
  return __uint_as_float(((unsigned)h) << 16);
}

// async global->LDS, 16B per lane. LDS dest must be wave-uniform base; HW adds lane*16.
__device__ __forceinline__ void async_copy16(const void* gptr, void* ldsptr) {
  __builtin_amdgcn_global_load_lds(
      (const __attribute__((address_space(1))) void*)gptr,
      (__attribute__((address_space(3))) void*)ldsptr,
      16, 0, 0);
}

// ---------------------------------------------------------------------------
// Kernel 1: features fp32 [M][D] -> bf16 [M][D], PLAIN row-major now
// (the LDS swizzle moved into fused_score's address math)
// ---------------------------------------------------------------------------
__global__ __launch_bounds__(256) void convert_f_bf16(
    const float4* __restrict__ src, ushort4* __restrict__ dst) {
  long i = (long)blockIdx.x * 256 + threadIdx.x;  // float4 index
  float4 v = src[i];
  ushort4 o;
  o.x = f2bf(v.x); o.y = f2bf(v.y); o.z = f2bf(v.z); o.w = f2bf(v.w);
  dst[i] = o;
}

// ---------------------------------------------------------------------------
// Kernel 2: W1 [D][U] fp32 -> W1T [U][D] bf16, plain row-major
// ---------------------------------------------------------------------------
__global__ __launch_bounds__(256) void transpose_w1(
    const float* __restrict__ W1, unsigned short* __restrict__ W1T) {
  __shared__ float tile[32][33];
  int tx = threadIdx.x & 31, ty = threadIdx.x >> 5;  // (32,8)
  int u0 = blockIdx.x * 32, k0 = blockIdx.y * 32;
#pragma unroll
  for (int i = ty; i < 32; i += 8) tile[i][tx] = W1[(long)(k0 + i) * U_ + u0 + tx];
  __syncthreads();
#pragma unroll
  for (int i = ty; i < 32; i += 8) {
    int u = u0 + i, k = k0 + tx;
    W1T[(long)u * D_ + k] = f2bf(tile[tx][i]);
  }
}

// ---------------------------------------------------------------------------
// Kernel 3: ph[b][u] = hidden[b][:] @ W2[:][u] + b1[u] + b2[u]   (fp32 exact)
// ---------------------------------------------------------------------------
__global__ __launch_bounds__(256) void proj_h_kernel(
    const float* __restrict__ hidden, const float* __restrict__ W2,
    const float* __restrict__ b1, const float* __restrict__ b2,
    float* __restrict__ ph) {
  int u = blockIdx.x * 256 + threadIdx.x;
  int bbase = blockIdx.y * 8;
  int h0 = blockIdx.z * 128;
  float acc[8];
  float bias = (blockIdx.z == 0) ? (b1[u] + b2[u]) : 0.0f;
#pragma unroll
  for (int i = 0; i < 8; ++i) acc[i] = bias;
  for (int h = h0; h < h0 + 128; ++h) {
    float w = W2[(long)h * U_ + u];
#pragma unroll
    for (int i = 0; i < 8; ++i) acc[i] += hidden[(bbase + i) * 1024 + h] * w;
  }
#pragma unroll
  for (int i = 0; i < 8; ++i) atomicAdd(&ph[(bbase + i) * U_ + u], acc[i]);
}

// ---------------------------------------------------------------------------
// Kernel 4: fused  logits[m] += sum_u tanh(A@W1 + ph) * V[u]
//
// 256x256 tile, BK=32, 512 thr (8 waves, 2M x 4N), 4-buffer LDS rotation
// (4 x 32KB = 128KB), staged 2 K-tiles ahead with global_load_lds, ONE counted
// s_waitcnt vmcnt(4) + raw s_barrier per K-tile (never drains to 0 in the main
// loop: T3+T4), setprio(1) around each 8-MFMA cluster (T5), st_16x32 LDS
// swizzle done via pre-swizzled per-lane GLOBAL source + swizzled ds_read
// (rule #21: LDS dest of global_load_lds stays linear).
//
// Safety of the counted wait (by construction):
//  - window W_t reads buf[t&3] (tile t), stages tile t+2 into buf[(t+2)&3]
//    which is distinct from both live read buffers and whose last reads ended
//    two window-barriers ago.
//  - at W_t end: outstanding = 4 loads of t+1 + 4 of t+2; vmcnt(4) ensures
//    t+1 fully landed BEFORE this wave's barrier; every wave does the same,
//    so after the barrier all of t+1 is visible to all waves.
// ---------------------------------------------------------------------------
#define LDA(rb, i) (*(const bf16x8*)&S[(rb) + arow + (i)*512])
#define LDB(rb, j) (*(const bf16x8*)&S[(rb) + 8192 + brow + (j)*512])
#define MM(i, j)                                                  \
  acc[i][j] = __builtin_amdgcn_mfma_f32_16x16x32_bf16(af[i], bf[j], \
                                                      acc[i][j], 0, 0, 0)
#define SYNC_MAIN \
  asm volatile("s_waitcnt vmcnt(4)" ::: "memory"); __builtin_amdgcn_s_barrier()
#define SYNC_LAST \
  asm volatile("s_waitcnt vmcnt(0)" ::: "memory"); __builtin_amdgcn_s_barrier()
#define SYNC_NONE ((void)0)

#define WINDOW(WT, DO_STAGE, ENDSYNC)                                          \
  {                                                                            \
    const int rb = ((WT) & 3) << 14;                                           \
    const int sb = (((WT) + 2) & 3) << 14;                                     \
    const int sk = ((WT) + 2) << 5;                                            \
    bf16x8 af[8], bf[4];                                                       \
    /* phase 0: Q(0,0) */                                                      \
    if (DO_STAGE) async_copy16(a0 + sk, &S[sb + (wave << 9)]);                 \
    af[0] = LDA(rb, 0); af[1] = LDA(rb, 1);                                    \
    af[2] = LDA(rb, 2); af[3] = LDA(rb, 3);                                    \
    bf[0] = LDB(rb, 0); bf[1] = LDB(rb, 1);                                    \
    __builtin_amdgcn_s_setprio(1);                                             \
    MM(0, 0); MM(0, 1); MM(1, 0); MM(1, 1);                                    \
    MM(2, 0); MM(2, 1); MM(3, 0); MM(3, 1);                                    \
    __builtin_amdgcn_s_setprio(0);                                             \
    __builtin_amdgcn_s_barrier();                                              \
    /* phase 1: Q(0,1) */                                                      \
    if (DO_STAGE) async_copy16(a1 + sk, &S[sb + 4096 + (wave << 9)]);          \
    bf[2] = LDB(rb, 2); bf[3] = LDB(rb, 3);                                    \
    __builtin_amdgcn_s_setprio(1);                                             \
    MM(0, 2); MM(0, 3); MM(1, 2); MM(1, 3);                                    \
    MM(2, 2); MM(2, 3); MM(3, 2); MM(3, 3);                                    \
    __builtin_amdgcn_s_setprio(0);                                             \
    __builtin_amdgcn_s_barrier();                                              \
    /* phase 2: Q(1,0) */                                                      \
    if (DO_STAGE) async_copy16(b0 + sk, &S[sb + 8192 + (wave << 9)]);          \
    af[4] = LDA(rb, 4); af[5] = LDA(rb, 5);                                    \
    af[6] = LDA(rb, 6); af[7] = LDA(rb, 7);                                    \
    __builtin_amdgcn_s_setprio(1);                                             \
    MM(4, 0); MM(4, 1); MM(5, 0); MM(5, 1);                                    \
    MM(6, 0); MM(6, 1); MM(7, 0); MM(7, 1);                                    \
    __builtin_amdgcn_s_setprio(0);                                             \
    __builtin_amdgcn_s_barrier();                                              \
    /* phase 3: Q(1,1) */                                                      \
    if (DO_STAGE) async_copy16(b1 + sk, &S[sb + 12288 + (wave << 9)]);         \
    __builtin_amdgcn_s_setprio(1);                                             \
    MM(4, 2); MM(4, 3); MM(5, 2); MM(5, 3);                                    \
    MM(6, 2); MM(6, 3); MM(7, 2); MM(7, 3);                                    \
    __builtin_amdgcn_s_setprio(0);                                             \
    ENDSYNC;                                                                   \
  }

__global__ __launch_bounds__(512, 2) void fused_score_kernel(
    const unsigned short* __restrict__ A,   // Fh  [M][1024] bf16 row-major
    const unsigned short* __restrict__ Bt,  // W1T [U][1024] bf16 row-major
    const float* __restrict__ ph,           // [B][U]
    const float* __restrict__ V,            // [U]
    float* __restrict__ logits) {           // [M] (zero-initialized)
  __shared__ unsigned short S[65536];  // 128 KB = 4 bufs x (A 8K-ush + B 8K-ush)

  const int tid = threadIdx.x;
  const int wave = tid >> 6;
  const int lane = tid & 63;
  const int l15 = lane & 15;
  const int quad = lane >> 4;
  const int wm = wave >> 2;  // 0..1 : 128-row half of the M-tile
  const int wn = wave & 3;   // 0..3 : 64-col slice of the N-tile

  // XCD-chunked bijective swizzle (nwg=1024, 8 XCDs, q=128): each XCD gets a
  // contiguous run of mtiles with all 4 of their ntiles -> A-panel L2 reuse.
  const int bid = blockIdx.x;
  const int wg = (bid & 7) * 128 + (bid >> 3);
  const int mtile = wg >> 2;   // 0..255
  const int ntile = wg & 3;    // 0..3
  const long m0 = (long)mtile * 256;
  const int n0 = ntile * 256;

  // --- staging source pointers (global pre-inverse-swizzled; LDS dest linear)
  // LDS linear byte P (within a 16KB A/B block): row = P/64, kbyte = P%64.
  // st_16x32: swz(P) = P ^ (((P>>9)&1)<<5); row bit3 == lane>>5 for our map.
  const int srow = (wave << 4) + (lane >> 2);                        // 0..127
  const int skel = ((lane & 3) << 3) ^ ((lane & 32) ? 16 : 0);       // elements
  const unsigned short* a0 = A + (m0 + srow) * 1024 + skel;
  const unsigned short* a1 = A + (m0 + 128 + srow) * 1024 + skel;
  const unsigned short* b0 = Bt + ((long)n0 + srow) * 1024 + skel;
  const unsigned short* b1 = Bt + ((long)n0 + 128 + srow) * 1024 + skel;

  // --- fragment ds_read offsets (ushort units), swizzled: XOR 16-ush when
  // row bit3 (= l15 bit3) set. 16B aligned.
  const int xorq = ((quad * 8) ^ ((l15 & 8) << 1));
  const int arow = (wm * 128 + l15) * 32 + xorq;
  const int brow = (wn * 64 + l15) * 32 + xorq;

  f32x4 acc[8][4];
#pragma unroll
  for (int i = 0; i < 8; ++i)
#pragma unroll
    for (int j = 0; j < 4; ++j) acc[i][j] = (f32x4){0.f, 0.f, 0.f, 0.f};

  // prologue: stage tiles 0 and 1 (order A0,A1,B0,B1 matches in-window order)
#pragma unroll
  for (int t = 0; t < 2; ++t) {
    const int sbase = t << 14;
    async_copy16(a0 + t * 32, &S[sbase + (wave << 9)]);
    async_copy16(a1 + t * 32, &S[sbase + 4096 + (wave << 9)]);
    async_copy16(b0 + t * 32, &S[sbase + 8192 + (wave << 9)]);
    async_copy16(b1 + t * 32, &S[sbase + 12288 + (wave << 9)]);
  }
  asm volatile("s_waitcnt vmcnt(4)" ::: "memory");  // tile 0 landed
  __builtin_amdgcn_s_barrier();

#pragma unroll 1
  for (int t = 0; t < 30; ++t) {
    WINDOW(t, 1, SYNC_MAIN)
  }
  WINDOW(30, 0, SYNC_LAST)
  WINDOW(31, 0, SYNC_NONE)

  // epilogue: s = tanh(acc + ph[b][u]); partial = s*V[u]; reduce over 16 lanes
  const int b = (int)(m0 >> 10);  // 256-row tile lies within one batch
  float phv[4], vv[4];
#pragma unroll
  for (int j = 0; j < 4; ++j) {
    int u = n0 + wn * 64 + j * 16 + l15;
    phv[j] = ph[b * U_ + u];
    vv[j] = V[u];
  }
#pragma unroll
  for (int i = 0; i < 8; ++i) {
#pragma unroll
    for (int r = 0; r < 4; ++r) {
      float part = 0.f;
#pragma unroll
      for (int j = 0; j < 4; ++j) {
        float s = acc[i][j][r] + phv[j];
        float e = __expf(2.0f * s);                        // inf-safe
        float th = 1.0f - 2.0f * __builtin_amdgcn_rcpf(e + 1.0f);
        part += th * vv[j];
      }
      // C/D layout: col = lane&15 (u) -> sum across the 16-lane group
      part += __shfl_xor(part, 1, 16);
      part += __shfl_xor(part, 2, 16);
      part += __shfl_xor(part, 4, 16);
      part += __shfl_xor(part, 8, 16);
      if (l15 == 0)
        atomicAdd(&logits[m0 + wm * 128 + i * 16 + quad * 4 + r], part);
    }
  }
}

// ---------------------------------------------------------------------------
// Kernel 5: softmax over L per batch (bV is a constant shift -> drops out)
// ---------------------------------------------------------------------------
__global__ __launch_bounds__(256) void softmax_kernel(
    const float* __restrict__ logits, float* __restrict__ wout) {
  __shared__ float redm[4];
  __shared__ float reds[4];
  int b = blockIdx.x;
  int tid = threadIdx.x;
  int wave = tid >> 6, lane = tid & 63;
  float4 v = *(const float4*)&logits[b * 1024 + tid * 4];
  float m = fmaxf(fmaxf(v.x, v.y), fmaxf(v.z, v.w));
#pragma unroll
  for (int off = 32; off >= 1; off >>= 1) m = fmaxf(m, __shfl_xor(m, off, 64));
  if (lane == 0) redm[wave] = m;
  __syncthreads();
  m = fmaxf(fmaxf(redm[0], redm[1]), fmaxf(redm[2], redm[3]));
  float e0 = __expf(v.x - m), e1 = __expf(v.y - m);
  float e2 = __expf(v.z - m), e3 = __expf(v.w - m);
  float s = e0 + e1 + e2 + e3;
#pragma unroll
  for (int off = 32; off >= 1; off >>= 1) s += __shfl_xor(s, off, 64);
  if (lane == 0) reds[wave] = s;
  __syncthreads();
  s = reds[0] + reds[1] + reds[2] + reds[3];
  float inv = 1.0f / s;
  float4 o = {e0 * inv, e1 * inv, e2 * inv, e3 * inv};
  *(float4*)&wout[b * 1024 + tid * 4] = o;
}

// ---------------------------------------------------------------------------
// Kernel 6: context[b][d] = sum_l w[b][l] * Fh[b][l][d]  (plain bf16 rows now;
// 2x more blocks than before: 64 l per block for latency hiding)
// ---------------------------------------------------------------------------
__global__ __launch_bounds__(256) void context_kernel(
    const unsigned short* __restrict__ Fh, const float* __restrict__ wv,
    float* __restrict__ out) {
  int b = blockIdx.x;
  int d4 = threadIdx.x * 4;
  int l0 = blockIdx.y * 64;
  const unsigned short* fp = Fh + ((long)b * 1024 + l0) * 1024;
  const float* wp = wv + b * 1024 + l0;
  float a0 = 0.f, a1 = 0.f, a2 = 0.f, a3 = 0.f;
#pragma unroll 4
  for (int l = 0; l < 64; ++l) {
    ushort4 f = *(const ushort4*)(fp + (long)l * 1024 + d4);
    float w = wp[l];
    a0 += w * bf2f(f.x);
    a1 += w * bf2f(f.y);
    a2 += w * bf2f(f.z);
    a3 += w * bf2f(f.w);
  }
  atomicAdd(&out[b * 1024 + d4 + 0], a0);
  atomicAdd(&out[b * 1024 + d4 + 1], a1);
  atomicAdd(&out[b * 1024 + d4 + 2], a2);
  atomicAdd(&out[b * 1024 + d4 + 3], a3);
}

// ---------------------------------------------------------------------------
extern "C" void kernel_launch(void* const* d_in, const int* in_sizes, int n_in,
                              void* d_out, int out_size, void* d_ws, size_t ws_size,
                              hipStream_t stream) {
  const float* features = (const float*)d_in[0];  // [64,1024,1024]
  const float* hidden   = (const float*)d_in[1];  // [64,1024]
  const float* W1       = (const float*)d_in[2];  // [1024,1024]
  const float* b1       = (const float*)d_in[3];  // [1024]
  const float* W2       = (const float*)d_in[4];  // [1024,1024]
  const float* b2       = (const float*)d_in[5];  // [1024]
  const float* V        = (const float*)d_in[6];  // [1024]
  // d_in[7] = bV: softmax is shift-invariant, unused.

  char* ws = (char*)d_ws;
  unsigned short* Fh  = (unsigned short*)ws;                          // 128 MB bf16 features (row-major)
  unsigned short* W1T = (unsigned short*)(ws + 134217728);            // 2 MB bf16 W1^T (row-major)
  float* ph     = (float*)(ws + 134217728 + 2097152);                 // 256 KB
  float* logits = (float*)(ws + 134217728 + 2097152 + 262144);        // 256 KB
  float* ctx  = (float*)d_out;            // [64,1024]
  float* wout = (float*)d_out + 65536;    // [64,1024] attention weights

  // zero atomic targets (ph+logits contiguous) and context output
  hipMemsetAsync(ph, 0, 262144 + 262144, stream);
  hipMemsetAsync(d_out, 0, 65536 * sizeof(float), stream);

  convert_f_bf16<<<65536, 256, 0, stream>>>((const float4*)features, (ushort4*)Fh);
  transpose_w1<<<dim3(32, 32), 256, 0, stream>>>(W1, W1T);
  proj_h_kernel<<<dim3(4, 8, 8), 256, 0, stream>>>(hidden, W2, b1, b2, ph);
  fused_score_kernel<<<1024, 512, 0, stream>>>(Fh, W1T, ph, V, logits);
  softmax_kernel<<<64, 256, 0, stream>>>(logits, wout);
  context_kernel<<<dim3(64, 16), 256, 0, stream>>>(Fh, wout, ctx);
}